// Round 1
// baseline (2311.725 us; speedup 1.0000x reference)
//
#include <hip/hip_runtime.h>
#include <math.h>

#define N_NODES   20000
#define N_EDGES   160000
#define N_LEDGES  1280000
#define IN_FEAT   128
#define HIDDEN    64
#define FEAT      128
#define OUT_FEAT  16
#define NUM_LAYERS 8
#define ALPHA     0.1f

// ---------------- lin0 + relu: h[20000,64] = relu(x @ w0 + b0) ----------------
__global__ __launch_bounds__(256) void k_lin0(const float* __restrict__ x,
                                              const float* __restrict__ w,
                                              const float* __restrict__ b,
                                              float* __restrict__ h) {
  int node = blockIdx.x * 4 + (threadIdx.x >> 6);
  int j = threadIdx.x & 63;
  if (node >= N_NODES) return;
  const float* xr = x + (size_t)node * IN_FEAT;
  float acc = b[j];
  #pragma unroll
  for (int k = 0; k < IN_FEAT; k++) acc = fmaf(xr[k], w[k * HIDDEN + j], acc);
  h[(size_t)node * HIDDEN + j] = fmaxf(acc, 0.f);
}

// ---------------- e[i] = [h[src[i]] || h[dst[i]]]; x0 = e ----------------
__global__ __launch_bounds__(256) void k_build_e(const int* __restrict__ src,
                                                 const int* __restrict__ dst,
                                                 const float* __restrict__ h,
                                                 float* __restrict__ e,
                                                 float* __restrict__ x0) {
  int gid = blockIdx.x * 256 + threadIdx.x;
  int edge = gid >> 5;          // 32 threads per edge (32 float4 = 128 floats)
  int p = gid & 31;
  if (edge >= N_EDGES) return;
  int n = (p < 16) ? src[edge] : dst[edge];
  float4 v = ((const float4*)(h + (size_t)n * HIDDEN))[p & 15];
  ((float4*)(e  + (size_t)edge * FEAT))[p] = v;
  ((float4*)(x0 + (size_t)edge * FEAT))[p] = v;
}

// ---------------- degree over col, count over row ----------------
__global__ __launch_bounds__(256) void k_count(const int* __restrict__ lrow,
                                               const int* __restrict__ lcol,
                                               int* __restrict__ deg,
                                               int* __restrict__ cnt) {
  int k = blockIdx.x * 256 + threadIdx.x;
  if (k >= N_LEDGES) return;
  atomicAdd(&deg[lcol[k]], 1);
  atomicAdd(&cnt[lrow[k]], 1);
}

__global__ __launch_bounds__(256) void k_dis(const int* __restrict__ deg,
                                             float* __restrict__ dis) {
  int i = blockIdx.x * 256 + threadIdx.x;
  if (i < N_EDGES) dis[i] = rsqrtf((float)(deg[i] + 1));  // +1 self-loop
}

// ---------------- exclusive scan of cnt -> row_ptr ----------------
__global__ __launch_bounds__(256) void k_scanA(const int* __restrict__ cnt,
                                               int* __restrict__ out,
                                               int* __restrict__ bsum) {
  __shared__ int sh[256];
  int tid = threadIdx.x;
  int base = blockIdx.x * 1024 + tid * 4;
  int v[4];
  #pragma unroll
  for (int i = 0; i < 4; i++) v[i] = (base + i < N_EDGES) ? cnt[base + i] : 0;
  int t = v[0] + v[1] + v[2] + v[3];
  sh[tid] = t;
  __syncthreads();
  for (int off = 1; off < 256; off <<= 1) {
    int xv = (tid >= off) ? sh[tid - off] : 0;
    __syncthreads();
    sh[tid] += xv;
    __syncthreads();
  }
  int run = sh[tid] - t;  // exclusive prefix of this thread within block
  #pragma unroll
  for (int i = 0; i < 4; i++) {
    if (base + i < N_EDGES) out[base + i] = run;
    run += v[i];
  }
  if (tid == 255) bsum[blockIdx.x] = sh[255];
}

__global__ void k_scanB(int* __restrict__ bsum, int nb) {
  if (blockIdx.x == 0 && threadIdx.x == 0) {
    int run = 0;
    for (int i = 0; i < nb; i++) { int v = bsum[i]; bsum[i] = run; run += v; }
  }
}

__global__ __launch_bounds__(256) void k_scanC(int* __restrict__ row_ptr,
                                               const int* __restrict__ bsum) {
  int tid = threadIdx.x;
  int base = blockIdx.x * 1024 + tid * 4;
  int add = bsum[blockIdx.x];
  #pragma unroll
  for (int i = 0; i < 4; i++)
    if (base + i < N_EDGES) row_ptr[base + i] += add;
  if (blockIdx.x == 0 && tid == 0) row_ptr[N_EDGES] = N_LEDGES;
}

// ---------------- fill CSR (col + val sorted by row) ----------------
__global__ __launch_bounds__(256) void k_fill(const int* __restrict__ lrow,
                                              const int* __restrict__ lcol,
                                              const int* __restrict__ row_ptr,
                                              int* __restrict__ cursor,
                                              const float* __restrict__ dis,
                                              int* __restrict__ cs,
                                              float* __restrict__ vs) {
  int k = blockIdx.x * 256 + threadIdx.x;
  if (k >= N_LEDGES) return;
  int r = lrow[k], c = lcol[k];
  int pos = row_ptr[r] + atomicAdd(&cursor[r], 1);
  cs[pos] = c;
  vs[pos] = dis[r] * dis[c];
}

// ---------------- SpMM + self-loop + alpha mix: m = 0.9*agg + 0.1*x0 ----------------
__global__ __launch_bounds__(256) void k_spmm(const int* __restrict__ row_ptr,
                                              const int* __restrict__ cs,
                                              const float* __restrict__ vs,
                                              const float* __restrict__ dis,
                                              const float* __restrict__ e,
                                              const float* __restrict__ x0,
                                              float* __restrict__ m) {
  int r = blockIdx.x * 4 + (threadIdx.x >> 6);
  if (r >= N_EDGES) return;
  int lane = threadIdx.x & 63;
  float d = dis[r];
  float2 es = ((const float2*)(e + (size_t)r * FEAT))[lane];
  float2 acc;
  acc.x = d * d * es.x;
  acc.y = d * d * es.y;
  int beg = row_ptr[r], end = row_ptr[r + 1];
  for (int t = beg; t < end; t++) {
    int c = cs[t];
    float v = vs[t];
    float2 ec = ((const float2*)(e + (size_t)c * FEAT))[lane];
    acc.x = fmaf(v, ec.x, acc.x);
    acc.y = fmaf(v, ec.y, acc.y);
  }
  float2 x0r = ((const float2*)(x0 + (size_t)r * FEAT))[lane];
  float2 o;
  o.x = fmaf(1.f - ALPHA, acc.x, ALPHA * x0r.x);
  o.y = fmaf(1.f - ALPHA, acc.y, ALPHA * x0r.y);
  ((float2*)(m + (size_t)r * FEAT))[lane] = o;
}

// ---------------- e = relu(M @ (cw*W + cm*I)), 128x128 tile fp32 ----------------
__global__ __launch_bounds__(256) void k_gemm(const float* __restrict__ M,
                                              const float* __restrict__ W,
                                              float* __restrict__ E,
                                              float cm, float cw) {
  __shared__ float As[32][132];  // [k][row], padded (row 528B, 16B aligned)
  __shared__ float Bs[32][132];  // [k][col]
  int tid = threadIdx.x;
  int ty = tid >> 4;   // 0..15
  int tx = tid & 15;   // 0..15
  int row0 = blockIdx.x * 128;

  float acc[8][8];
  #pragma unroll
  for (int i = 0; i < 8; i++)
    #pragma unroll
    for (int j = 0; j < 8; j++) acc[i][j] = 0.f;

  for (int k0 = 0; k0 < FEAT; k0 += 32) {
    // stage A: 128 rows x 32 k
    {
      int r = tid >> 3;            // 0..31
      int kkb = (tid & 7) << 2;    // 0,4,..,28
      #pragma unroll
      for (int i = 0; i < 4; i++) {
        const float4 v = *(const float4*)(M + (size_t)(row0 + r + i * 32) * FEAT + k0 + kkb);
        As[kkb + 0][r + i * 32] = v.x;
        As[kkb + 1][r + i * 32] = v.y;
        As[kkb + 2][r + i * 32] = v.z;
        As[kkb + 3][r + i * 32] = v.w;
      }
    }
    // stage B with identity fold: Bs[k][c] = cw*W[k][c] + (k==c)*cm
    {
      int kkb = tid >> 5;          // 0..7
      int c = (tid & 31) << 2;     // 0..124
      #pragma unroll
      for (int i = 0; i < 4; i++) {
        int kk = kkb + i * 8;
        int kg = k0 + kk;
        float4 v = *(const float4*)(W + (size_t)kg * FEAT + c);
        v.x *= cw; v.y *= cw; v.z *= cw; v.w *= cw;
        if (kg >= c && kg < c + 4) (&v.x)[kg - c] += cm;
        *(float4*)(&Bs[kk][c]) = v;
      }
    }
    __syncthreads();
    #pragma unroll
    for (int kk = 0; kk < 32; kk++) {
      float a[8], b[8];
      *(float4*)&a[0] = *(const float4*)&As[kk][ty * 4];
      *(float4*)&a[4] = *(const float4*)&As[kk][64 + ty * 4];
      *(float4*)&b[0] = *(const float4*)&Bs[kk][tx * 4];
      *(float4*)&b[4] = *(const float4*)&Bs[kk][64 + tx * 4];
      #pragma unroll
      for (int i = 0; i < 8; i++)
        #pragma unroll
        for (int j = 0; j < 8; j++)
          acc[i][j] = fmaf(a[i], b[j], acc[i][j]);
    }
    __syncthreads();
  }
  // epilogue: relu + store
  #pragma unroll
  for (int i = 0; i < 8; i++) {
    int r = row0 + ((i < 4) ? (ty * 4 + i) : (64 + ty * 4 + i - 4));
    float4 o0, o1;
    o0.x = fmaxf(acc[i][0], 0.f); o0.y = fmaxf(acc[i][1], 0.f);
    o0.z = fmaxf(acc[i][2], 0.f); o0.w = fmaxf(acc[i][3], 0.f);
    o1.x = fmaxf(acc[i][4], 0.f); o1.y = fmaxf(acc[i][5], 0.f);
    o1.z = fmaxf(acc[i][6], 0.f); o1.w = fmaxf(acc[i][7], 0.f);
    *(float4*)(E + (size_t)r * FEAT + tx * 4) = o0;
    *(float4*)(E + (size_t)r * FEAT + 64 + tx * 4) = o1;
  }
}

// ---------------- out = e @ w1 + b1 ----------------
__global__ __launch_bounds__(256) void k_lin1(const float* __restrict__ E,
                                              const float* __restrict__ W1,
                                              const float* __restrict__ b1,
                                              float* __restrict__ out) {
  __shared__ float wt[16][132];  // transposed w1: wt[c][k], padded
  int tid = threadIdx.x;
  for (int i = tid; i < FEAT * OUT_FEAT; i += 256) {
    int k = i >> 4, c = i & 15;
    wt[c][k] = W1[i];
  }
  __syncthreads();
  int gid = blockIdx.x * 256 + tid;
  int row = gid >> 4;
  int c = gid & 15;
  if (row >= N_EDGES) return;
  const float4* er = (const float4*)(E + (size_t)row * FEAT);
  const float4* wr = (const float4*)&wt[c][0];
  float acc = b1[c];
  #pragma unroll
  for (int q = 0; q < 32; q++) {
    float4 a = er[q], w = wr[q];
    acc = fmaf(a.x, w.x, acc); acc = fmaf(a.y, w.y, acc);
    acc = fmaf(a.z, w.z, acc); acc = fmaf(a.w, w.w, acc);
  }
  out[(size_t)row * OUT_FEAT + c] = acc;
}

extern "C" void kernel_launch(void* const* d_in, const int* in_sizes, int n_in,
                              void* d_out, int out_size, void* d_ws, size_t ws_size,
                              hipStream_t stream) {
  const float* x   = (const float*)d_in[0];
  const int*   ei  = (const int*)d_in[1];
  const int*   lei = (const int*)d_in[2];
  const float* w0  = (const float*)d_in[3];
  const float* b0  = (const float*)d_in[4];
  const float* cw  = (const float*)d_in[5];
  const float* w1  = (const float*)d_in[6];
  const float* b1  = (const float*)d_in[7];
  float* out = (float*)d_out;

  char* ws = (char*)d_ws;
  size_t off = 0;
  auto alloc = [&](size_t bytes) -> void* {
    void* p = ws + off;
    off += (bytes + 255) & ~(size_t)255;
    return p;
  };
  float* h      = (float*)alloc((size_t)N_NODES * HIDDEN * 4);
  float* x0     = (float*)alloc((size_t)N_EDGES * FEAT * 4);
  float* e      = (float*)alloc((size_t)N_EDGES * FEAT * 4);
  float* m      = (float*)alloc((size_t)N_EDGES * FEAT * 4);
  int*   deg    = (int*)alloc((size_t)N_EDGES * 4);
  float* dis    = (float*)alloc((size_t)N_EDGES * 4);
  int*   cnt    = (int*)alloc((size_t)N_EDGES * 4);
  int*   cursor = (int*)alloc((size_t)N_EDGES * 4);
  int*   row_ptr= (int*)alloc((size_t)(N_EDGES + 1) * 4);
  int*   cs     = (int*)alloc((size_t)N_LEDGES * 4);
  float* vs     = (float*)alloc((size_t)N_LEDGES * 4);
  int*   bsum   = (int*)alloc(256 * 4);

  hipMemsetAsync(deg, 0, (size_t)N_EDGES * 4, stream);
  hipMemsetAsync(cnt, 0, (size_t)N_EDGES * 4, stream);
  hipMemsetAsync(cursor, 0, (size_t)N_EDGES * 4, stream);

  k_lin0<<<(N_NODES + 3) / 4, 256, 0, stream>>>(x, w0, b0, h);
  k_build_e<<<(N_EDGES * 32 + 255) / 256, 256, 0, stream>>>(ei, ei + N_EDGES, h, e, x0);
  k_count<<<(N_LEDGES + 255) / 256, 256, 0, stream>>>(lei, lei + N_LEDGES, deg, cnt);
  k_dis<<<(N_EDGES + 255) / 256, 256, 0, stream>>>(deg, dis);
  const int nscan = (N_EDGES + 1023) / 1024;  // 157
  k_scanA<<<nscan, 256, 0, stream>>>(cnt, row_ptr, bsum);
  k_scanB<<<1, 64, 0, stream>>>(bsum, nscan);
  k_scanC<<<nscan, 256, 0, stream>>>(row_ptr, bsum);
  k_fill<<<(N_LEDGES + 255) / 256, 256, 0, stream>>>(lei, lei + N_LEDGES, row_ptr, cursor, dis, cs, vs);

  for (int l = 0; l < NUM_LAYERS; l++) {
    float beta = logf(0.5f / (float)(l + 1) + 1.0f);
    k_spmm<<<(N_EDGES + 3) / 4, 256, 0, stream>>>(row_ptr, cs, vs, dis, e, x0, m);
    k_gemm<<<N_EDGES / 128, 256, 0, stream>>>(m, cw + (size_t)l * FEAT * FEAT, e, 1.0f - beta, beta);
  }
  k_lin1<<<(N_EDGES * OUT_FEAT + 255) / 256, 256, 0, stream>>>(e, w1, b1, out);
}

// Round 2
// 1186.770 us; speedup vs baseline: 1.9479x; 1.9479x over previous
//
#include <hip/hip_runtime.h>
#include <math.h>

#define N_NODES   20000
#define N_EDGES   160000
#define N_LEDGES  1280000
#define IN_FEAT   128
#define HIDDEN    64
#define FEAT      128
#define OUT_FEAT  16
#define NUM_LAYERS 8
#define ALPHA     0.1f

typedef __attribute__((ext_vector_type(4))) float f32x4;
typedef __attribute__((ext_vector_type(8))) short bf16x8;

__device__ __forceinline__ float2 bf2(uint u) {
  union { uint i; float f; } a, b;
  a.i = u << 16;
  b.i = u & 0xffff0000u;
  float2 r; r.x = a.f; r.y = b.f; return r;
}
__device__ __forceinline__ ushort f2bf(float f) {
  union { float f; uint i; } u; u.f = f;
  uint r = u.i + 0x7fffu + ((u.i >> 16) & 1u);
  return (ushort)(r >> 16);
}
__device__ __forceinline__ uint pack2(float x, float y) {
  return (uint)f2bf(x) | ((uint)f2bf(y) << 16);
}

// ---------------- lin0 + relu: h[20000,64] = relu(x @ w0 + b0) ----------------
__global__ __launch_bounds__(256) void k_lin0(const float* __restrict__ x,
                                              const float* __restrict__ w,
                                              const float* __restrict__ b,
                                              float* __restrict__ h) {
  int node = blockIdx.x * 4 + (threadIdx.x >> 6);
  int j = threadIdx.x & 63;
  if (node >= N_NODES) return;
  const float* xr = x + (size_t)node * IN_FEAT;
  float acc = b[j];
  #pragma unroll
  for (int k = 0; k < IN_FEAT; k++) acc = fmaf(xr[k], w[k * HIDDEN + j], acc);
  h[(size_t)node * HIDDEN + j] = fmaxf(acc, 0.f);
}

// ---------------- e[i] = [h[src[i]] || h[dst[i]]] (bf16); x0 = e ----------------
__global__ __launch_bounds__(256) void k_build_e(const int* __restrict__ src,
                                                 const int* __restrict__ dst,
                                                 const float* __restrict__ h,
                                                 ushort* __restrict__ e,
                                                 ushort* __restrict__ x0) {
  int gid = blockIdx.x * 256 + threadIdx.x;
  int edge = gid >> 5;          // 32 threads per edge
  int p = gid & 31;
  if (edge >= N_EDGES) return;
  int n = (p < 16) ? src[edge] : dst[edge];
  float4 v = ((const float4*)(h + (size_t)n * HIDDEN))[p & 15];
  uint2 pk;
  pk.x = pack2(v.x, v.y);
  pk.y = pack2(v.z, v.w);
  ((uint2*)(e  + ((size_t)edge << 7)))[p] = pk;
  ((uint2*)(x0 + ((size_t)edge << 7)))[p] = pk;
}

// ---------------- degree over col, count over row ----------------
__global__ __launch_bounds__(256) void k_count(const int* __restrict__ lrow,
                                               const int* __restrict__ lcol,
                                               int* __restrict__ deg,
                                               int* __restrict__ cnt) {
  int k = blockIdx.x * 256 + threadIdx.x;
  if (k >= N_LEDGES) return;
  atomicAdd(&deg[lcol[k]], 1);
  atomicAdd(&cnt[lrow[k]], 1);
}

__global__ __launch_bounds__(256) void k_dis(const int* __restrict__ deg,
                                             float* __restrict__ dis) {
  int i = blockIdx.x * 256 + threadIdx.x;
  if (i < N_EDGES) dis[i] = rsqrtf((float)(deg[i] + 1));  // +1 self-loop
}

// ---------------- exclusive scan of cnt -> row_ptr ----------------
__global__ __launch_bounds__(256) void k_scanA(const int* __restrict__ cnt,
                                               int* __restrict__ out,
                                               int* __restrict__ bsum) {
  __shared__ int sh[256];
  int tid = threadIdx.x;
  int base = blockIdx.x * 1024 + tid * 4;
  int v[4];
  #pragma unroll
  for (int i = 0; i < 4; i++) v[i] = (base + i < N_EDGES) ? cnt[base + i] : 0;
  int t = v[0] + v[1] + v[2] + v[3];
  sh[tid] = t;
  __syncthreads();
  for (int off = 1; off < 256; off <<= 1) {
    int xv = (tid >= off) ? sh[tid - off] : 0;
    __syncthreads();
    sh[tid] += xv;
    __syncthreads();
  }
  int run = sh[tid] - t;
  #pragma unroll
  for (int i = 0; i < 4; i++) {
    if (base + i < N_EDGES) out[base + i] = run;
    run += v[i];
  }
  if (tid == 255) bsum[blockIdx.x] = sh[255];
}

__global__ void k_scanB(int* __restrict__ bsum, int nb) {
  __shared__ int sh[256];
  int tid = threadIdx.x;
  int v = (tid < nb) ? bsum[tid] : 0;
  sh[tid] = v;
  __syncthreads();
  for (int off = 1; off < 256; off <<= 1) {
    int xv = (tid >= off) ? sh[tid - off] : 0;
    __syncthreads();
    sh[tid] += xv;
    __syncthreads();
  }
  if (tid < nb) bsum[tid] = sh[tid] - v;  // exclusive
}

__global__ __launch_bounds__(256) void k_scanC(int* __restrict__ row_ptr,
                                               const int* __restrict__ bsum) {
  int tid = threadIdx.x;
  int base = blockIdx.x * 1024 + tid * 4;
  int add = bsum[blockIdx.x];
  #pragma unroll
  for (int i = 0; i < 4; i++)
    if (base + i < N_EDGES) row_ptr[base + i] += add;
  if (blockIdx.x == 0 && tid == 0) row_ptr[N_EDGES] = N_LEDGES;
}

// ---------------- fill CSR ----------------
__global__ __launch_bounds__(256) void k_fill(const int* __restrict__ lrow,
                                              const int* __restrict__ lcol,
                                              const int* __restrict__ row_ptr,
                                              int* __restrict__ cursor,
                                              const float* __restrict__ dis,
                                              int* __restrict__ cs,
                                              float* __restrict__ vs) {
  int k = blockIdx.x * 256 + threadIdx.x;
  if (k >= N_LEDGES) return;
  int r = lrow[k], c = lcol[k];
  int pos = row_ptr[r] + atomicAdd(&cursor[r], 1);
  cs[pos] = c;
  vs[pos] = dis[r] * dis[c];
}

// ---------------- precompute Bt[l][c][k] = bf16(beta*W[l][k][c] + (k==c)*(1-beta)) ----------------
__global__ __launch_bounds__(256) void k_prepw(const float* __restrict__ W,
                                               ushort* __restrict__ Bt) {
  int gid = blockIdx.x * 256 + threadIdx.x;
  if (gid >= NUM_LAYERS * FEAT * FEAT) return;
  int l = gid >> 14;
  int rem = gid & 16383;
  int k = rem >> 7, c = rem & 127;
  float beta = logf(0.5f / (float)(l + 1) + 1.0f);
  float v = beta * W[gid];
  if (k == c) v += 1.0f - beta;
  Bt[(l << 14) + (c << 7) + k] = f2bf(v);
}

// ---------------- SpMM + self-loop + alpha mix (bf16 storage, fp32 accum) ----------------
__global__ __launch_bounds__(256) void k_spmm(const int* __restrict__ row_ptr,
                                              const int* __restrict__ cs,
                                              const float* __restrict__ vs,
                                              const float* __restrict__ dis,
                                              const ushort* __restrict__ e,
                                              const ushort* __restrict__ x0,
                                              ushort* __restrict__ m) {
  int r = blockIdx.x * 4 + (threadIdx.x >> 6);
  if (r >= N_EDGES) return;
  int lane = threadIdx.x & 63;
  const uint* eu = (const uint*)e;
  float d = dis[r];
  float2 es = bf2(eu[((size_t)r << 6) + lane]);
  float dd = d * d;
  float a0x = dd * es.x, a0y = dd * es.y;
  float a1x = 0.f, a1y = 0.f;
  int t = row_ptr[r], end = row_ptr[r + 1];
  for (; t + 2 <= end; t += 2) {
    int c0 = cs[t], c1 = cs[t + 1];
    float v0 = vs[t], v1 = vs[t + 1];
    uint u0 = eu[((size_t)c0 << 6) + lane];
    uint u1 = eu[((size_t)c1 << 6) + lane];
    float2 f0 = bf2(u0), f1 = bf2(u1);
    a0x = fmaf(v0, f0.x, a0x); a0y = fmaf(v0, f0.y, a0y);
    a1x = fmaf(v1, f1.x, a1x); a1y = fmaf(v1, f1.y, a1y);
  }
  if (t < end) {
    int c0 = cs[t]; float v0 = vs[t];
    float2 f0 = bf2(eu[((size_t)c0 << 6) + lane]);
    a0x = fmaf(v0, f0.x, a0x); a0y = fmaf(v0, f0.y, a0y);
  }
  float2 xr = bf2(((const uint*)x0)[((size_t)r << 6) + lane]);
  float ox = fmaf(1.f - ALPHA, a0x + a1x, ALPHA * xr.x);
  float oy = fmaf(1.f - ALPHA, a0y + a1y, ALPHA * xr.y);
  ((uint*)m)[((size_t)r << 6) + lane] = pack2(ox, oy);
}

// ---------------- e = relu(M @ Bt^T) via bf16 MFMA, 128x128 tile, K=128 ----------------
__global__ __launch_bounds__(256) void k_gemm(const ushort* __restrict__ M,
                                              const ushort* __restrict__ Bt,
                                              ushort* __restrict__ E) {
  __shared__ __align__(16) ushort As[128 * 128];  // [row][k], XOR-swizzled
  __shared__ __align__(16) ushort Bs[128 * 128];  // [col][k], XOR-swizzled
  int tid = threadIdx.x;
  int row0 = blockIdx.x * 128;
  #pragma unroll
  for (int it = 0; it < 8; it++) {
    int u = it * 256 + tid;
    int r = u >> 4, kb = u & 15;
    int byte_off = (kb * 16) ^ ((r & 7) << 4);
    uint4 va = *(const uint4*)(M + (((size_t)(row0 + r)) << 7) + kb * 8);
    *(uint4*)((char*)As + r * 256 + byte_off) = va;
    uint4 vb = *(const uint4*)(Bt + (((size_t)r) << 7) + kb * 8);
    *(uint4*)((char*)Bs + r * 256 + byte_off) = vb;
  }
  __syncthreads();
  int wv = tid >> 6, lane = tid & 63;
  int l15 = lane & 15, l4 = lane >> 4;
  f32x4 acc[8][2];
  #pragma unroll
  for (int i = 0; i < 8; i++) { acc[i][0] = (f32x4)0; acc[i][1] = (f32x4)0; }
  #pragma unroll
  for (int kb = 0; kb < 4; kb++) {
    int kbyte = kb * 64 + l4 * 16;
    bf16x8 bfr[2];
    #pragma unroll
    for (int n = 0; n < 2; n++) {
      int c = wv * 32 + n * 16 + l15;
      bfr[n] = *(const bf16x8*)((const char*)Bs + c * 256 + (kbyte ^ ((c & 7) << 4)));
    }
    #pragma unroll
    for (int mr = 0; mr < 8; mr++) {
      int rr = mr * 16 + l15;
      bf16x8 afr = *(const bf16x8*)((const char*)As + rr * 256 + (kbyte ^ ((rr & 7) << 4)));
      acc[mr][0] = __builtin_amdgcn_mfma_f32_16x16x32_bf16(afr, bfr[0], acc[mr][0], 0, 0, 0);
      acc[mr][1] = __builtin_amdgcn_mfma_f32_16x16x32_bf16(afr, bfr[1], acc[mr][1], 0, 0, 0);
    }
  }
  // epilogue: relu + bf16 store (C/D layout: col=lane&15, row=(lane>>4)*4+reg)
  #pragma unroll
  for (int mr = 0; mr < 8; mr++) {
    #pragma unroll
    for (int n = 0; n < 2; n++) {
      int col = wv * 32 + n * 16 + l15;
      int rowb = row0 + mr * 16 + l4 * 4;
      #pragma unroll
      for (int j = 0; j < 4; j++) {
        float v = fmaxf(acc[mr][n][j], 0.f);
        E[((size_t)(rowb + j) << 7) + col] = f2bf(v);
      }
    }
  }
}

// ---------------- out = e @ w1 + b1 (bf16 e, fp32 out) ----------------
__global__ __launch_bounds__(256) void k_lin1(const ushort* __restrict__ E,
                                              const float* __restrict__ W1,
                                              const float* __restrict__ b1,
                                              float* __restrict__ out) {
  __shared__ float wt[16][132];
  int tid = threadIdx.x;
  for (int i = tid; i < FEAT * OUT_FEAT; i += 256) {
    int k = i >> 4, c = i & 15;
    wt[c][k] = W1[i];
  }
  __syncthreads();
  int gid = blockIdx.x * 256 + tid;
  int row = gid >> 4;
  int c = gid & 15;
  if (row >= N_EDGES) return;
  const uint4* er = (const uint4*)(E + ((size_t)row << 7));
  float acc = b1[c];
  #pragma unroll
  for (int q = 0; q < 16; q++) {
    uint4 u = er[q];
    const float* w = &wt[c][q * 8];
    float2 f0 = bf2(u.x), f1 = bf2(u.y), f2v = bf2(u.z), f3 = bf2(u.w);
    acc = fmaf(f0.x, w[0], acc); acc = fmaf(f0.y, w[1], acc);
    acc = fmaf(f1.x, w[2], acc); acc = fmaf(f1.y, w[3], acc);
    acc = fmaf(f2v.x, w[4], acc); acc = fmaf(f2v.y, w[5], acc);
    acc = fmaf(f3.x, w[6], acc); acc = fmaf(f3.y, w[7], acc);
  }
  out[(size_t)row * OUT_FEAT + c] = acc;
}

extern "C" void kernel_launch(void* const* d_in, const int* in_sizes, int n_in,
                              void* d_out, int out_size, void* d_ws, size_t ws_size,
                              hipStream_t stream) {
  const float* x   = (const float*)d_in[0];
  const int*   ei  = (const int*)d_in[1];
  const int*   lei = (const int*)d_in[2];
  const float* w0  = (const float*)d_in[3];
  const float* b0  = (const float*)d_in[4];
  const float* cw  = (const float*)d_in[5];
  const float* w1  = (const float*)d_in[6];
  const float* b1  = (const float*)d_in[7];
  float* out = (float*)d_out;

  char* ws = (char*)d_ws;
  size_t off = 0;
  auto alloc = [&](size_t bytes) -> void* {
    void* p = ws + off;
    off += (bytes + 255) & ~(size_t)255;
    return p;
  };
  float*  h      = (float*)alloc((size_t)N_NODES * HIDDEN * 4);
  ushort* x0     = (ushort*)alloc((size_t)N_EDGES * FEAT * 2);
  ushort* e      = (ushort*)alloc((size_t)N_EDGES * FEAT * 2);
  ushort* m      = (ushort*)alloc((size_t)N_EDGES * FEAT * 2);
  ushort* Btp    = (ushort*)alloc((size_t)NUM_LAYERS * FEAT * FEAT * 2);
  int*    deg    = (int*)alloc((size_t)N_EDGES * 4);
  float*  dis    = (float*)alloc((size_t)N_EDGES * 4);
  int*    cnt    = (int*)alloc((size_t)N_EDGES * 4);
  int*    cursor = (int*)alloc((size_t)N_EDGES * 4);
  int*    row_ptr= (int*)alloc((size_t)(N_EDGES + 1) * 4);
  int*    cs     = (int*)alloc((size_t)N_LEDGES * 4);
  float*  vs     = (float*)alloc((size_t)N_LEDGES * 4);
  int*    bsum   = (int*)alloc(256 * 4);

  hipMemsetAsync(deg, 0, (size_t)N_EDGES * 4, stream);
  hipMemsetAsync(cnt, 0, (size_t)N_EDGES * 4, stream);
  hipMemsetAsync(cursor, 0, (size_t)N_EDGES * 4, stream);

  k_lin0<<<(N_NODES + 3) / 4, 256, 0, stream>>>(x, w0, b0, h);
  k_build_e<<<(N_EDGES * 32 + 255) / 256, 256, 0, stream>>>(ei, ei + N_EDGES, h, e, x0);
  k_count<<<(N_LEDGES + 255) / 256, 256, 0, stream>>>(lei, lei + N_LEDGES, deg, cnt);
  k_dis<<<(N_EDGES + 255) / 256, 256, 0, stream>>>(deg, dis);
  const int nscan = (N_EDGES + 1023) / 1024;  // 157
  k_scanA<<<nscan, 256, 0, stream>>>(cnt, row_ptr, bsum);
  k_scanB<<<1, 256, 0, stream>>>(bsum, nscan);
  k_scanC<<<nscan, 256, 0, stream>>>(row_ptr, bsum);
  k_fill<<<(N_LEDGES + 255) / 256, 256, 0, stream>>>(lei, lei + N_LEDGES, row_ptr, cursor, dis, cs, vs);
  k_prepw<<<(NUM_LAYERS * FEAT * FEAT + 255) / 256, 256, 0, stream>>>(cw, Btp);

  for (int l = 0; l < NUM_LAYERS; l++) {
    k_spmm<<<(N_EDGES + 3) / 4, 256, 0, stream>>>(row_ptr, cs, vs, dis, e, x0, m);
    k_gemm<<<N_EDGES / 128, 256, 0, stream>>>(m, Btp + ((size_t)l << 14), e);
  }
  k_lin1<<<(N_EDGES * OUT_FEAT + 255) / 256, 256, 0, stream>>>(e, w1, b1, out);
}

// Round 3
// 1161.886 us; speedup vs baseline: 1.9896x; 1.0214x over previous
//
#include <hip/hip_runtime.h>
#include <math.h>

#define N_NODES   20000
#define N_EDGES   160000
#define N_LEDGES  1280000
#define IN_FEAT   128
#define HIDDEN    64
#define FEAT      128
#define OUT_FEAT  16
#define NUM_LAYERS 8
#define ALPHA     0.1f

typedef __attribute__((ext_vector_type(4))) float f32x4;
typedef __attribute__((ext_vector_type(8))) short bf16x8;

__device__ __forceinline__ float2 bf2(uint u) {
  union { uint i; float f; } a, b;
  a.i = u << 16;
  b.i = u & 0xffff0000u;
  float2 r; r.x = a.f; r.y = b.f; return r;
}
__device__ __forceinline__ ushort f2bf(float f) {
  union { float f; uint i; } u; u.f = f;
  uint r = u.i + 0x7fffu + ((u.i >> 16) & 1u);
  return (ushort)(r >> 16);
}
__device__ __forceinline__ uint pack2(float x, float y) {
  return (uint)f2bf(x) | ((uint)f2bf(y) << 16);
}

// ---------------- lin0 + relu: h[20000,64] = relu(x @ w0 + b0) ----------------
__global__ __launch_bounds__(256) void k_lin0(const float* __restrict__ x,
                                              const float* __restrict__ w,
                                              const float* __restrict__ b,
                                              float* __restrict__ h) {
  int node = blockIdx.x * 4 + (threadIdx.x >> 6);
  int j = threadIdx.x & 63;
  if (node >= N_NODES) return;
  const float* xr = x + (size_t)node * IN_FEAT;
  float acc = b[j];
  #pragma unroll
  for (int k = 0; k < IN_FEAT; k++) acc = fmaf(xr[k], w[k * HIDDEN + j], acc);
  h[(size_t)node * HIDDEN + j] = fmaxf(acc, 0.f);
}

// ---------------- e[i] = [h[src[i]] || h[dst[i]]] (bf16); x0 = e ----------------
__global__ __launch_bounds__(256) void k_build_e(const int* __restrict__ src,
                                                 const int* __restrict__ dst,
                                                 const float* __restrict__ h,
                                                 ushort* __restrict__ e,
                                                 ushort* __restrict__ x0) {
  int gid = blockIdx.x * 256 + threadIdx.x;
  int edge = gid >> 5;          // 32 threads per edge
  int p = gid & 31;
  if (edge >= N_EDGES) return;
  int n = (p < 16) ? src[edge] : dst[edge];
  float4 v = ((const float4*)(h + (size_t)n * HIDDEN))[p & 15];
  uint2 pk;
  pk.x = pack2(v.x, v.y);
  pk.y = pack2(v.z, v.w);
  ((uint2*)(e  + ((size_t)edge << 7)))[p] = pk;
  ((uint2*)(x0 + ((size_t)edge << 7)))[p] = pk;
}

// ---------------- degree over col, count over row ----------------
__global__ __launch_bounds__(256) void k_count(const int* __restrict__ lrow,
                                               const int* __restrict__ lcol,
                                               int* __restrict__ deg,
                                               int* __restrict__ cnt) {
  int k = blockIdx.x * 256 + threadIdx.x;
  if (k >= N_LEDGES) return;
  atomicAdd(&deg[lcol[k]], 1);
  atomicAdd(&cnt[lrow[k]], 1);
}

__global__ __launch_bounds__(256) void k_dis(const int* __restrict__ deg,
                                             float* __restrict__ dis) {
  int i = blockIdx.x * 256 + threadIdx.x;
  if (i < N_EDGES) dis[i] = rsqrtf((float)(deg[i] + 1));  // +1 self-loop
}

// ---------------- exclusive scan of cnt -> row_ptr ----------------
__global__ __launch_bounds__(256) void k_scanA(const int* __restrict__ cnt,
                                               int* __restrict__ out,
                                               int* __restrict__ bsum) {
  __shared__ int sh[256];
  int tid = threadIdx.x;
  int base = blockIdx.x * 1024 + tid * 4;
  int v[4];
  #pragma unroll
  for (int i = 0; i < 4; i++) v[i] = (base + i < N_EDGES) ? cnt[base + i] : 0;
  int t = v[0] + v[1] + v[2] + v[3];
  sh[tid] = t;
  __syncthreads();
  for (int off = 1; off < 256; off <<= 1) {
    int xv = (tid >= off) ? sh[tid - off] : 0;
    __syncthreads();
    sh[tid] += xv;
    __syncthreads();
  }
  int run = sh[tid] - t;
  #pragma unroll
  for (int i = 0; i < 4; i++) {
    if (base + i < N_EDGES) out[base + i] = run;
    run += v[i];
  }
  if (tid == 255) bsum[blockIdx.x] = sh[255];
}

__global__ void k_scanB(int* __restrict__ bsum, int nb) {
  __shared__ int sh[256];
  int tid = threadIdx.x;
  int v = (tid < nb) ? bsum[tid] : 0;
  sh[tid] = v;
  __syncthreads();
  for (int off = 1; off < 256; off <<= 1) {
    int xv = (tid >= off) ? sh[tid - off] : 0;
    __syncthreads();
    sh[tid] += xv;
    __syncthreads();
  }
  if (tid < nb) bsum[tid] = sh[tid] - v;  // exclusive
}

__global__ __launch_bounds__(256) void k_scanC(int* __restrict__ row_ptr,
                                               const int* __restrict__ bsum) {
  int tid = threadIdx.x;
  int base = blockIdx.x * 1024 + tid * 4;
  int add = bsum[blockIdx.x];
  #pragma unroll
  for (int i = 0; i < 4; i++)
    if (base + i < N_EDGES) row_ptr[base + i] += add;
  if (blockIdx.x == 0 && tid == 0) row_ptr[N_EDGES] = N_LEDGES;
}

// ---------------- fill CSR: pv[pos] = {col, val} ; consumes cnt via atomicSub ----------------
__global__ __launch_bounds__(256) void k_fill(const int* __restrict__ lrow,
                                              const int* __restrict__ lcol,
                                              const int* __restrict__ row_ptr,
                                              int* __restrict__ cnt,
                                              const float* __restrict__ dis,
                                              uint2* __restrict__ pv) {
  int k = blockIdx.x * 256 + threadIdx.x;
  if (k >= N_LEDGES) return;
  int r = lrow[k], c = lcol[k];
  int pos = row_ptr[r] + atomicSub(&cnt[r], 1) - 1;
  uint2 out;
  out.x = (uint)c;
  out.y = __float_as_uint(dis[r] * dis[c]);
  pv[pos] = out;
}

// ---------------- precompute Bt[l][c][k] = bf16(beta*W[l][k][c] + (k==c)*(1-beta)) ----------------
__global__ __launch_bounds__(256) void k_prepw(const float* __restrict__ W,
                                               ushort* __restrict__ Bt) {
  int gid = blockIdx.x * 256 + threadIdx.x;
  if (gid >= NUM_LAYERS * FEAT * FEAT) return;
  int l = gid >> 14;
  int rem = gid & 16383;
  int k = rem >> 7, c = rem & 127;
  float beta = logf(0.5f / (float)(l + 1) + 1.0f);
  float v = beta * W[gid];
  if (k == c) v += 1.0f - beta;
  Bt[(l << 14) + (c << 7) + k] = f2bf(v);
}

// ---------------- fused layer: SpMM(+self-loop,+alpha-mix) -> LDS -> MFMA GEMM -> relu -> e_out ----------------
// 64-row tile per block, 256 threads (4 waves). A-tile in swizzled LDS (bf16),
// B (identity-folded weights) in registers from L2-hot global.
__global__ __launch_bounds__(256, 4) void k_layer(const int* __restrict__ row_ptr,
                                                  const uint2* __restrict__ pv,
                                                  const float* __restrict__ dis,
                                                  const ushort* __restrict__ e_in,
                                                  const ushort* __restrict__ x0,
                                                  const ushort* __restrict__ Bt,
                                                  ushort* __restrict__ e_out) {
  __shared__ __align__(16) ushort As[64 * 128];  // [row][k], XOR-swizzled, 16KB
  int tid = threadIdx.x;
  int wv = tid >> 6, lane = tid & 63;
  int l15 = lane & 15, l4 = lane >> 4;
  int row0 = blockIdx.x * 64;

  // B fragments: col = wv*32 + n*16 + l15, k = kb*32 + l4*8 .. +8
  bf16x8 bfr[2][4];
  #pragma unroll
  for (int n = 0; n < 2; n++) {
    const char* bp = (const char*)Bt + (size_t)(wv * 32 + n * 16 + l15) * 256;
    #pragma unroll
    for (int kb = 0; kb < 4; kb++)
      bfr[n][kb] = *(const bf16x8*)(bp + kb * 64 + l4 * 16);
  }

  const uint* eu  = (const uint*)e_in;
  const uint* x0u = (const uint*)x0;

  // gather phase: 16 rows per wave, 4-way unrolled over edges
  for (int i = 0; i < 16; i++) {
    int rl = wv * 16 + i;
    int r = row0 + rl;
    float d = dis[r];
    float2 es = bf2(eu[((size_t)r << 6) + lane]);
    float dd = d * d;
    float ax0 = dd * es.x, ay0 = dd * es.y;
    float ax1 = 0.f, ay1 = 0.f, ax2 = 0.f, ay2 = 0.f, ax3 = 0.f, ay3 = 0.f;
    int t = row_ptr[r], end = row_ptr[r + 1];
    for (; t + 4 <= end; t += 4) {
      uint2 p0 = pv[t], p1 = pv[t + 1], p2 = pv[t + 2], p3 = pv[t + 3];
      uint u0 = eu[((size_t)p0.x << 6) + lane];
      uint u1 = eu[((size_t)p1.x << 6) + lane];
      uint u2 = eu[((size_t)p2.x << 6) + lane];
      uint u3 = eu[((size_t)p3.x << 6) + lane];
      float v0 = __uint_as_float(p0.y), v1 = __uint_as_float(p1.y);
      float v2 = __uint_as_float(p2.y), v3 = __uint_as_float(p3.y);
      float2 f0 = bf2(u0), f1 = bf2(u1), f2v = bf2(u2), f3 = bf2(u3);
      ax0 = fmaf(v0, f0.x, ax0);  ay0 = fmaf(v0, f0.y, ay0);
      ax1 = fmaf(v1, f1.x, ax1);  ay1 = fmaf(v1, f1.y, ay1);
      ax2 = fmaf(v2, f2v.x, ax2); ay2 = fmaf(v2, f2v.y, ay2);
      ax3 = fmaf(v3, f3.x, ax3);  ay3 = fmaf(v3, f3.y, ay3);
    }
    for (; t < end; t++) {
      uint2 p0 = pv[t];
      float v0 = __uint_as_float(p0.y);
      float2 f0 = bf2(eu[((size_t)p0.x << 6) + lane]);
      ax0 = fmaf(v0, f0.x, ax0); ay0 = fmaf(v0, f0.y, ay0);
    }
    float2 xr = bf2(x0u[((size_t)r << 6) + lane]);
    float ox = fmaf(1.f - ALPHA, (ax0 + ax1) + (ax2 + ax3), ALPHA * xr.x);
    float oy = fmaf(1.f - ALPHA, (ay0 + ay1) + (ay2 + ay3), ALPHA * xr.y);
    *(uint*)((char*)As + rl * 256 + ((lane * 4) ^ ((rl & 7) << 4))) = pack2(ox, oy);
  }
  __syncthreads();

  // MFMA phase: out 64x128, per wave 64x32 (cols wv*32..+32)
  f32x4 acc[4][2];
  #pragma unroll
  for (int i = 0; i < 4; i++) { acc[i][0] = (f32x4)0; acc[i][1] = (f32x4)0; }
  #pragma unroll
  for (int kb = 0; kb < 4; kb++) {
    int kbyte = kb * 64 + l4 * 16;
    #pragma unroll
    for (int mr = 0; mr < 4; mr++) {
      int rr = mr * 16 + l15;
      bf16x8 afr = *(const bf16x8*)((const char*)As + rr * 256 + (kbyte ^ ((rr & 7) << 4)));
      acc[mr][0] = __builtin_amdgcn_mfma_f32_16x16x32_bf16(afr, bfr[0][kb], acc[mr][0], 0, 0, 0);
      acc[mr][1] = __builtin_amdgcn_mfma_f32_16x16x32_bf16(afr, bfr[1][kb], acc[mr][1], 0, 0, 0);
    }
  }
  // epilogue: relu + bf16 store (C/D: col=lane&15, row=(lane>>4)*4+reg)
  #pragma unroll
  for (int mr = 0; mr < 4; mr++) {
    #pragma unroll
    for (int n = 0; n < 2; n++) {
      int col = wv * 32 + n * 16 + l15;
      int rowb = row0 + mr * 16 + l4 * 4;
      #pragma unroll
      for (int j = 0; j < 4; j++) {
        float v = fmaxf(acc[mr][n][j], 0.f);
        e_out[((size_t)(rowb + j) << 7) + col] = f2bf(v);
      }
    }
  }
}

// ---------------- out = e @ w1 + b1 (bf16 e, fp32 out) ----------------
__global__ __launch_bounds__(256) void k_lin1(const ushort* __restrict__ E,
                                              const float* __restrict__ W1,
                                              const float* __restrict__ b1,
                                              float* __restrict__ out) {
  __shared__ float wt[16][132];
  int tid = threadIdx.x;
  for (int i = tid; i < FEAT * OUT_FEAT; i += 256) {
    int k = i >> 4, c = i & 15;
    wt[c][k] = W1[i];
  }
  __syncthreads();
  int gid = blockIdx.x * 256 + tid;
  int row = gid >> 4;
  int c = gid & 15;
  if (row >= N_EDGES) return;
  const uint4* er = (const uint4*)(E + ((size_t)row << 7));
  float acc = b1[c];
  #pragma unroll
  for (int q = 0; q < 16; q++) {
    uint4 u = er[q];
    const float* w = &wt[c][q * 8];
    float2 f0 = bf2(u.x), f1 = bf2(u.y), f2v = bf2(u.z), f3 = bf2(u.w);
    acc = fmaf(f0.x, w[0], acc); acc = fmaf(f0.y, w[1], acc);
    acc = fmaf(f1.x, w[2], acc); acc = fmaf(f1.y, w[3], acc);
    acc = fmaf(f2v.x, w[4], acc); acc = fmaf(f2v.y, w[5], acc);
    acc = fmaf(f3.x, w[6], acc); acc = fmaf(f3.y, w[7], acc);
  }
  out[(size_t)row * OUT_FEAT + c] = acc;
}

extern "C" void kernel_launch(void* const* d_in, const int* in_sizes, int n_in,
                              void* d_out, int out_size, void* d_ws, size_t ws_size,
                              hipStream_t stream) {
  const float* x   = (const float*)d_in[0];
  const int*   ei  = (const int*)d_in[1];
  const int*   lei = (const int*)d_in[2];
  const float* w0  = (const float*)d_in[3];
  const float* b0  = (const float*)d_in[4];
  const float* cw  = (const float*)d_in[5];
  const float* w1  = (const float*)d_in[6];
  const float* b1  = (const float*)d_in[7];
  float* out = (float*)d_out;

  char* ws = (char*)d_ws;
  size_t off = 0;
  auto alloc = [&](size_t bytes) -> void* {
    void* p = ws + off;
    off += (bytes + 255) & ~(size_t)255;
    return p;
  };
  float*  h      = (float*)alloc((size_t)N_NODES * HIDDEN * 4);
  ushort* x0     = (ushort*)alloc((size_t)N_EDGES * FEAT * 2);
  ushort* eA     = (ushort*)alloc((size_t)N_EDGES * FEAT * 2);
  ushort* eB     = (ushort*)alloc((size_t)N_EDGES * FEAT * 2);
  ushort* Btp    = (ushort*)alloc((size_t)NUM_LAYERS * FEAT * FEAT * 2);
  int*    deg    = (int*)alloc((size_t)N_EDGES * 4);
  float*  dis    = (float*)alloc((size_t)N_EDGES * 4);
  int*    cnt    = (int*)alloc((size_t)N_EDGES * 4);
  int*    row_ptr= (int*)alloc((size_t)(N_EDGES + 1) * 4);
  uint2*  pv     = (uint2*)alloc((size_t)N_LEDGES * 8);
  int*    bsum   = (int*)alloc(256 * 4);

  hipMemsetAsync(deg, 0, (size_t)N_EDGES * 4, stream);
  hipMemsetAsync(cnt, 0, (size_t)N_EDGES * 4, stream);

  k_lin0<<<(N_NODES + 3) / 4, 256, 0, stream>>>(x, w0, b0, h);
  k_build_e<<<(N_EDGES * 32 + 255) / 256, 256, 0, stream>>>(ei, ei + N_EDGES, h, eA, x0);
  k_count<<<(N_LEDGES + 255) / 256, 256, 0, stream>>>(lei, lei + N_LEDGES, deg, cnt);
  k_dis<<<(N_EDGES + 255) / 256, 256, 0, stream>>>(deg, dis);
  const int nscan = (N_EDGES + 1023) / 1024;  // 157
  k_scanA<<<nscan, 256, 0, stream>>>(cnt, row_ptr, bsum);
  k_scanB<<<1, 256, 0, stream>>>(bsum, nscan);
  k_scanC<<<nscan, 256, 0, stream>>>(row_ptr, bsum);
  k_fill<<<(N_LEDGES + 255) / 256, 256, 0, stream>>>(lei, lei + N_LEDGES, row_ptr, cnt, dis, pv);
  k_prepw<<<(NUM_LAYERS * FEAT * FEAT + 255) / 256, 256, 0, stream>>>(cw, Btp);

  ushort* ein = eA;
  ushort* eout = eB;
  for (int l = 0; l < NUM_LAYERS; l++) {
    k_layer<<<N_EDGES / 64, 256, 0, stream>>>(row_ptr, pv, dis, ein, x0,
                                              Btp + ((size_t)l << 14), eout);
    ushort* t = ein; ein = eout; eout = t;
  }
  k_lin1<<<(N_EDGES * OUT_FEAT + 255) / 256, 256, 0, stream>>>(ein, w1, b1, out);
}

// Round 4
// 1082.276 us; speedup vs baseline: 2.1360x; 1.0736x over previous
//
#include <hip/hip_runtime.h>
#include <math.h>

#define N_NODES   20000
#define N_EDGES   160000
#define N_LEDGES  1280000
#define N_TOTE    (N_LEDGES + N_EDGES)   // edges incl. self-loops
#define IN_FEAT   128
#define HIDDEN    64
#define FEAT      128
#define OUT_FEAT  16
#define NUM_LAYERS 8
#define ALPHA     0.1f
#define CHUNK     4

typedef __attribute__((ext_vector_type(4))) float f32x4;
typedef __attribute__((ext_vector_type(8))) short bf16x8;

__device__ __forceinline__ float2 bf2(uint u) {
  union { uint i; float f; } a, b;
  a.i = u << 16;
  b.i = u & 0xffff0000u;
  float2 r; r.x = a.f; r.y = b.f; return r;
}
__device__ __forceinline__ ushort f2bf(float f) {
  union { float f; uint i; } u; u.f = f;
  uint r = u.i + 0x7fffu + ((u.i >> 16) & 1u);
  return (ushort)(r >> 16);
}
__device__ __forceinline__ uint pack2(float x, float y) {
  return (uint)f2bf(x) | ((uint)f2bf(y) << 16);
}

// ---------------- lin0 + relu ----------------
__global__ __launch_bounds__(256) void k_lin0(const float* __restrict__ x,
                                              const float* __restrict__ w,
                                              const float* __restrict__ b,
                                              float* __restrict__ h) {
  int node = blockIdx.x * 4 + (threadIdx.x >> 6);
  int j = threadIdx.x & 63;
  if (node >= N_NODES) return;
  const float* xr = x + (size_t)node * IN_FEAT;
  float acc = b[j];
  #pragma unroll
  for (int k = 0; k < IN_FEAT; k++) acc = fmaf(xr[k], w[k * HIDDEN + j], acc);
  h[(size_t)node * HIDDEN + j] = fmaxf(acc, 0.f);
}

// ---------------- e[i] = [h[src]||h[dst]] (bf16); x0 = e ----------------
__global__ __launch_bounds__(256) void k_build_e(const int* __restrict__ src,
                                                 const int* __restrict__ dst,
                                                 const float* __restrict__ h,
                                                 ushort* __restrict__ e,
                                                 ushort* __restrict__ x0) {
  int gid = blockIdx.x * 256 + threadIdx.x;
  int edge = gid >> 5;
  int p = gid & 31;
  if (edge >= N_EDGES) return;
  int n = (p < 16) ? src[edge] : dst[edge];
  float4 v = ((const float4*)(h + (size_t)n * HIDDEN))[p & 15];
  uint2 pk;
  pk.x = pack2(v.x, v.y);
  pk.y = pack2(v.z, v.w);
  ((uint2*)(e  + ((size_t)edge << 7)))[p] = pk;
  ((uint2*)(x0 + ((size_t)edge << 7)))[p] = pk;
}

// ---------------- init: deg=0, cnt=1 (self-loop pre-counted) ----------------
__global__ __launch_bounds__(256) void k_init(int* __restrict__ deg,
                                              int* __restrict__ cnt) {
  int i = blockIdx.x * 256 + threadIdx.x;
  if (i < N_EDGES) { deg[i] = 0; cnt[i] = 1; }
}

// ---------------- degree over col, count over row ----------------
__global__ __launch_bounds__(256) void k_count(const int* __restrict__ lrow,
                                               const int* __restrict__ lcol,
                                               int* __restrict__ deg,
                                               int* __restrict__ cnt) {
  int k = blockIdx.x * 256 + threadIdx.x;
  if (k >= N_LEDGES) return;
  atomicAdd(&deg[lcol[k]], 1);
  atomicAdd(&cnt[lrow[k]], 1);
}

__global__ __launch_bounds__(256) void k_dis(const int* __restrict__ deg,
                                             float* __restrict__ dis) {
  int i = blockIdx.x * 256 + threadIdx.x;
  if (i < N_EDGES) dis[i] = rsqrtf((float)(deg[i] + 1));  // +1 self-loop
}

// ---------------- exclusive scan of cnt -> row_ptr ----------------
__global__ __launch_bounds__(256) void k_scanA(const int* __restrict__ cnt,
                                               int* __restrict__ out,
                                               int* __restrict__ bsum) {
  __shared__ int sh[256];
  int tid = threadIdx.x;
  int base = blockIdx.x * 1024 + tid * 4;
  int v[4];
  #pragma unroll
  for (int i = 0; i < 4; i++) v[i] = (base + i < N_EDGES) ? cnt[base + i] : 0;
  int t = v[0] + v[1] + v[2] + v[3];
  sh[tid] = t;
  __syncthreads();
  for (int off = 1; off < 256; off <<= 1) {
    int xv = (tid >= off) ? sh[tid - off] : 0;
    __syncthreads();
    sh[tid] += xv;
    __syncthreads();
  }
  int run = sh[tid] - t;
  #pragma unroll
  for (int i = 0; i < 4; i++) {
    if (base + i < N_EDGES) out[base + i] = run;
    run += v[i];
  }
  if (tid == 255) bsum[blockIdx.x] = sh[255];
}

__global__ void k_scanB(int* __restrict__ bsum, int nb) {
  __shared__ int sh[256];
  int tid = threadIdx.x;
  int v = (tid < nb) ? bsum[tid] : 0;
  sh[tid] = v;
  __syncthreads();
  for (int off = 1; off < 256; off <<= 1) {
    int xv = (tid >= off) ? sh[tid - off] : 0;
    __syncthreads();
    sh[tid] += xv;
    __syncthreads();
  }
  if (tid < nb) bsum[tid] = sh[tid] - v;  // exclusive
}

__global__ __launch_bounds__(256) void k_scanC(int* __restrict__ row_ptr,
                                               const int* __restrict__ bsum) {
  int tid = threadIdx.x;
  int base = blockIdx.x * 1024 + tid * 4;
  int add = bsum[blockIdx.x];
  #pragma unroll
  for (int i = 0; i < 4; i++)
    if (base + i < N_EDGES) row_ptr[base + i] += add;
  if (blockIdx.x == 0 && tid == 0) row_ptr[N_EDGES] = N_TOTE;
}

// ---------------- fill CSR: pv[pos] = {col, 0.9*val} ----------------
__global__ __launch_bounds__(256) void k_fill(const int* __restrict__ lrow,
                                              const int* __restrict__ lcol,
                                              const int* __restrict__ row_ptr,
                                              int* __restrict__ cnt,
                                              const float* __restrict__ dis,
                                              uint2* __restrict__ pv) {
  int k = blockIdx.x * 256 + threadIdx.x;
  if (k >= N_LEDGES) return;
  int r = lrow[k], c = lcol[k];
  int pos = row_ptr[r] + atomicSub(&cnt[r], 1) - 1;
  uint2 out;
  out.x = (uint)c;
  out.y = __float_as_uint((1.f - ALPHA) * dis[r] * dis[c]);
  pv[pos] = out;
}

// self-loop edges: pv entry {r, 0.9*dis[r]^2}
__global__ __launch_bounds__(256) void k_fill_self(const int* __restrict__ row_ptr,
                                                   int* __restrict__ cnt,
                                                   const float* __restrict__ dis,
                                                   uint2* __restrict__ pv) {
  int r = blockIdx.x * 256 + threadIdx.x;
  if (r >= N_EDGES) return;
  int pos = row_ptr[r] + atomicSub(&cnt[r], 1) - 1;
  float d = dis[r];
  uint2 out;
  out.x = (uint)r;
  out.y = __float_as_uint((1.f - ALPHA) * d * d);
  pv[pos] = out;
}

// ---------------- Bt[c][k] = bf16(beta*W[k][c] + (k==c)*(1-beta)); Bt2 = 0.1*Bt ----------------
__global__ __launch_bounds__(256) void k_prepw(const float* __restrict__ W,
                                               ushort* __restrict__ Bt,
                                               ushort* __restrict__ Bt2) {
  int gid = blockIdx.x * 256 + threadIdx.x;
  if (gid >= NUM_LAYERS * FEAT * FEAT) return;
  int l = gid >> 14;
  int rem = gid & 16383;
  int k = rem >> 7, c = rem & 127;
  float beta = logf(0.5f / (float)(l + 1) + 1.0f);
  float v = beta * W[gid];
  if (k == c) v += 1.0f - beta;
  int o = (l << 14) + (c << 7) + k;
  Bt[o]  = f2bf(v);
  Bt2[o] = f2bf(ALPHA * v);
}

// ---------------- fused layer: segmented-stream SpMM -> LDS -> MFMA ----------------
// e_out = relu(agg' @ W' + x0 @ W2), agg' = 0.9*(sym-norm SpMM incl self-loop)
__global__ __launch_bounds__(256, 4) void k_layer(const int* __restrict__ row_ptr,
                                                  const uint2* __restrict__ pv,
                                                  const ushort* __restrict__ e_in,
                                                  const ushort* __restrict__ x0,
                                                  const ushort* __restrict__ Bt,
                                                  const ushort* __restrict__ Bt2,
                                                  ushort* __restrict__ e_out) {
  __shared__ __align__(16) ushort As[64 * 128];  // [row][k], XOR-swizzled, 16KB
  int tid = threadIdx.x;
  int wv = tid >> 6, lane = tid & 63;
  int l15 = lane & 15, l4 = lane >> 4;
  int row0 = blockIdx.x * 64;
  int r0w = row0 + wv * 16;                 // this wave's first row

  // wave's row_ptr slice in registers (lanes 0..16 hold row_ptr[r0w+lane])
  int rpidx = r0w + lane;
  if (rpidx > N_EDGES) rpidx = N_EDGES;
  int myrp = row_ptr[rpidx];

  int t    = __builtin_amdgcn_readfirstlane(__shfl(myrp, 0));
  int tend = __builtin_amdgcn_readfirstlane(__shfl(myrp, 16));
  int r    = r0w;
  int end  = __builtin_amdgcn_readfirstlane(__shfl(myrp, 1));

  const uint* eu = (const uint*)e_in;
  float ax = 0.f, ay = 0.f;

  uint cA[CHUNK], uA[CHUNK]; float vA[CHUNK];
  uint cB[CHUNK], uB[CHUNK]; float vB[CHUNK];

  auto loadpv = [&](int tb_, uint* cc, float* vv) {
    #pragma unroll
    for (int j = 0; j < CHUNK; j++) {
      int tj = tb_ + j;
      uint2 p = pv[tj];                       // padded array: unguarded load
      bool valid = (tj < tend);
      cc[j] = valid ? p.x : (uint)r0w;
      vv[j] = valid ? __uint_as_float(p.y) : 0.f;
    }
  };
  auto gather = [&](const uint* cc, uint* uu) {
    #pragma unroll
    for (int j = 0; j < CHUNK; j++) {
      int cu = __builtin_amdgcn_readfirstlane((int)cc[j]);
      uu[j] = eu[((size_t)cu << 6) + lane];
    }
  };
  auto flush = [&]() {
    int rl = r - row0;
    *(uint*)((char*)As + rl * 256 + ((lane * 4) ^ ((rl & 7) << 4))) = pack2(ax, ay);
    ax = 0.f; ay = 0.f;
  };
  auto consume = [&](int tb_, const uint* cc, const float* vv, const uint* uu) {
    #pragma unroll
    for (int j = 0; j < CHUNK; j++) {
      int tj = tb_ + j;
      if (tj < tend) {
        while (tj >= end) {                    // row boundary (wave-uniform)
          flush();
          r++;
          end = __builtin_amdgcn_readfirstlane(__shfl(myrp, r - r0w + 1));
        }
        float2 f = bf2(uu[j]);
        ax = fmaf(vv[j], f.x, ax);
        ay = fmaf(vv[j], f.y, ay);
      }
    }
  };

  // software-pipelined segmented stream: 2 chunks (8 gathers) in flight
  int tb = t;
  loadpv(tb, cA, vA); gather(cA, uA);
  while (true) {
    if (tb + CHUNK < tend) { loadpv(tb + CHUNK, cB, vB); gather(cB, uB); }
    consume(tb, cA, vA, uA);
    tb += CHUNK;
    if (tb >= tend) break;
    if (tb + CHUNK < tend) { loadpv(tb + CHUNK, cA, vA); gather(cA, uA); }
    consume(tb, cB, vB, uB);
    tb += CHUNK;
    if (tb >= tend) break;
  }
  flush();  // last row (every row has >=1 edge via self-loop)
  __syncthreads();

  // MFMA phase: acc = As @ W' + x0tile @ W2 ; per wave 64x32 output
  f32x4 acc[4][2];
  #pragma unroll
  for (int i = 0; i < 4; i++) { acc[i][0] = (f32x4)0; acc[i][1] = (f32x4)0; }
  const char* btA  = (const char*)Bt  + (size_t)(wv * 32 + l15) * 256;
  const char* btB  = btA + 16 * 256;
  const char* bt2A = (const char*)Bt2 + (size_t)(wv * 32 + l15) * 256;
  const char* bt2B = bt2A + 16 * 256;
  const char* x0b  = (const char*)x0 + ((size_t)row0 << 8);
  #pragma unroll
  for (int kb = 0; kb < 4; kb++) {
    int kbyte = kb * 64 + l4 * 16;
    bf16x8 b0 = *(const bf16x8*)(btA + kbyte);
    bf16x8 b1 = *(const bf16x8*)(btB + kbyte);
    bf16x8 q0 = *(const bf16x8*)(bt2A + kbyte);
    bf16x8 q1 = *(const bf16x8*)(bt2B + kbyte);
    #pragma unroll
    for (int mr = 0; mr < 4; mr++) {
      int rr = mr * 16 + l15;
      bf16x8 afr = *(const bf16x8*)((const char*)As + rr * 256 + (kbyte ^ ((rr & 7) << 4)));
      bf16x8 xfr = *(const bf16x8*)(x0b + (size_t)rr * 256 + kbyte);
      acc[mr][0] = __builtin_amdgcn_mfma_f32_16x16x32_bf16(afr, b0, acc[mr][0], 0, 0, 0);
      acc[mr][1] = __builtin_amdgcn_mfma_f32_16x16x32_bf16(afr, b1, acc[mr][1], 0, 0, 0);
      acc[mr][0] = __builtin_amdgcn_mfma_f32_16x16x32_bf16(xfr, q0, acc[mr][0], 0, 0, 0);
      acc[mr][1] = __builtin_amdgcn_mfma_f32_16x16x32_bf16(xfr, q1, acc[mr][1], 0, 0, 0);
    }
  }
  // epilogue: relu + bf16 store (C/D: col=lane&15, row=(lane>>4)*4+reg)
  #pragma unroll
  for (int mr = 0; mr < 4; mr++) {
    #pragma unroll
    for (int n = 0; n < 2; n++) {
      int col = wv * 32 + n * 16 + l15;
      int rowb = row0 + mr * 16 + l4 * 4;
      #pragma unroll
      for (int j = 0; j < 4; j++) {
        float v = fmaxf(acc[mr][n][j], 0.f);
        e_out[((size_t)(rowb + j) << 7) + col] = f2bf(v);
      }
    }
  }
}

// ---------------- out = e @ w1 + b1 ----------------
__global__ __launch_bounds__(256) void k_lin1(const ushort* __restrict__ E,
                                              const float* __restrict__ W1,
                                              const float* __restrict__ b1,
                                              float* __restrict__ out) {
  __shared__ float wt[16][132];
  int tid = threadIdx.x;
  for (int i = tid; i < FEAT * OUT_FEAT; i += 256) {
    int k = i >> 4, c = i & 15;
    wt[c][k] = W1[i];
  }
  __syncthreads();
  int gid = blockIdx.x * 256 + tid;
  int row = gid >> 4;
  int c = gid & 15;
  if (row >= N_EDGES) return;
  const uint4* er = (const uint4*)(E + ((size_t)row << 7));
  float acc = b1[c];
  #pragma unroll
  for (int q = 0; q < 16; q++) {
    uint4 u = er[q];
    const float* w = &wt[c][q * 8];
    float2 f0 = bf2(u.x), f1 = bf2(u.y), f2v = bf2(u.z), f3 = bf2(u.w);
    acc = fmaf(f0.x, w[0], acc); acc = fmaf(f0.y, w[1], acc);
    acc = fmaf(f1.x, w[2], acc); acc = fmaf(f1.y, w[3], acc);
    acc = fmaf(f2v.x, w[4], acc); acc = fmaf(f2v.y, w[5], acc);
    acc = fmaf(f3.x, w[6], acc); acc = fmaf(f3.y, w[7], acc);
  }
  out[(size_t)row * OUT_FEAT + c] = acc;
}

extern "C" void kernel_launch(void* const* d_in, const int* in_sizes, int n_in,
                              void* d_out, int out_size, void* d_ws, size_t ws_size,
                              hipStream_t stream) {
  const float* x   = (const float*)d_in[0];
  const int*   ei  = (const int*)d_in[1];
  const int*   lei = (const int*)d_in[2];
  const float* w0  = (const float*)d_in[3];
  const float* b0  = (const float*)d_in[4];
  const float* cw  = (const float*)d_in[5];
  const float* w1  = (const float*)d_in[6];
  const float* b1  = (const float*)d_in[7];
  float* out = (float*)d_out;

  char* ws = (char*)d_ws;
  size_t off = 0;
  auto alloc = [&](size_t bytes) -> void* {
    void* p = ws + off;
    off += (bytes + 255) & ~(size_t)255;
    return p;
  };
  float*  h      = (float*)alloc((size_t)N_NODES * HIDDEN * 4);
  ushort* x0     = (ushort*)alloc((size_t)N_EDGES * FEAT * 2);
  ushort* eA     = (ushort*)alloc((size_t)N_EDGES * FEAT * 2);
  ushort* eB     = (ushort*)alloc((size_t)N_EDGES * FEAT * 2);
  ushort* Btp    = (ushort*)alloc((size_t)NUM_LAYERS * FEAT * FEAT * 2);
  ushort* Btp2   = (ushort*)alloc((size_t)NUM_LAYERS * FEAT * FEAT * 2);
  int*    deg    = (int*)alloc((size_t)N_EDGES * 4);
  float*  dis    = (float*)alloc((size_t)N_EDGES * 4);
  int*    cnt    = (int*)alloc((size_t)N_EDGES * 4);
  int*    row_ptr= (int*)alloc((size_t)(N_EDGES + 1) * 4);
  uint2*  pv     = (uint2*)alloc(((size_t)N_TOTE + 16) * 8);  // +pad for unguarded loads
  int*    bsum   = (int*)alloc(256 * 4);

  k_lin0<<<(N_NODES + 3) / 4, 256, 0, stream>>>(x, w0, b0, h);
  k_build_e<<<(N_EDGES * 32 + 255) / 256, 256, 0, stream>>>(ei, ei + N_EDGES, h, eA, x0);
  k_init<<<(N_EDGES + 255) / 256, 256, 0, stream>>>(deg, cnt);
  k_count<<<(N_LEDGES + 255) / 256, 256, 0, stream>>>(lei, lei + N_LEDGES, deg, cnt);
  k_dis<<<(N_EDGES + 255) / 256, 256, 0, stream>>>(deg, dis);
  const int nscan = (N_EDGES + 1023) / 1024;  // 157
  k_scanA<<<nscan, 256, 0, stream>>>(cnt, row_ptr, bsum);
  k_scanB<<<1, 256, 0, stream>>>(bsum, nscan);
  k_scanC<<<nscan, 256, 0, stream>>>(row_ptr, bsum);
  k_fill<<<(N_LEDGES + 255) / 256, 256, 0, stream>>>(lei, lei + N_LEDGES, row_ptr, cnt, dis, pv);
  k_fill_self<<<(N_EDGES + 255) / 256, 256, 0, stream>>>(row_ptr, cnt, dis, pv);
  k_prepw<<<(NUM_LAYERS * FEAT * FEAT + 255) / 256, 256, 0, stream>>>(cw, Btp, Btp2);

  ushort* ein = eA;
  ushort* eout = eB;
  for (int l = 0; l < NUM_LAYERS; l++) {
    k_layer<<<N_EDGES / 64, 256, 0, stream>>>(row_ptr, pv, ein, x0,
                                              Btp + ((size_t)l << 14),
                                              Btp2 + ((size_t)l << 14), eout);
    ushort* t = ein; ein = eout; eout = t;
  }
  k_lin1<<<(N_EDGES * OUT_FEAT + 255) / 256, 256, 0, stream>>>(ein, w1, b1, out);
}